// Round 13
// baseline (338.087 us; speedup 1.0000x reference)
//
#include <hip/hip_runtime.h>
#include <hip/hip_bf16.h>
#include <cstdint>
#include <cstddef>

#define SEQ    4096
#define DM     2048
#define DH     128
#define NH     16
#define NKV    4
#define NC     3072          // qkv output columns: 2048 q | 512 k | 512 v
#define KOFF   2048
#define VOFF   2560
// 1/sqrt(128) * log2(e): q pre-scale so softmax runs in base-2 (exp2)
#define Q_SCALE 0.12751730f

using bf16 = __hip_bfloat16;
typedef __bf16 bf16x8 __attribute__((ext_vector_type(8)));
typedef float f32x4 __attribute__((ext_vector_type(4)));
typedef float f32x16 __attribute__((ext_vector_type(16)));

static __device__ inline float bf2f(bf16 x) { return __bfloat162float(x); }
static __device__ inline bf16 f2bf(float x) { return __float2bfloat16(x); }

// async global->LDS, 16B per lane. LDS dest = wave-uniform base + lane*16.
static __device__ inline void load_lds16(const bf16* g, bf16* l) {
    __builtin_amdgcn_global_load_lds(
        (const __attribute__((address_space(1))) uint32_t*)g,
        (__attribute__((address_space(3))) uint32_t*)l, 16, 0, 0);
}

// ---------------- x: f32 -> bf16 ----------------
__global__ void xconv(const float* __restrict__ in, bf16* __restrict__ out) {
    int i = blockIdx.x * 256 + threadIdx.x;   // one float4 per thread
    float4 v = ((const float4*)in)[i];
    bf16 a = f2bf(v.x), b = f2bf(v.y), c = f2bf(v.z), d = f2bf(v.w);
    ushort4 u;
    u.x = *(unsigned short*)&a; u.y = *(unsigned short*)&b;
    u.z = *(unsigned short*)&c; u.w = *(unsigned short*)&d;
    ((ushort4*)out)[i] = u;
}

// ---------------- prep: LDS-tiled weight transposes (f32 -> bf16) ----------------
__global__ void prep_wqkv(const float* __restrict__ WQ, const float* __restrict__ WK,
                          const float* __restrict__ WV, bf16* __restrict__ wt) {
    __shared__ float tl[64][65];
    const int t = threadIdx.x;
    const int m0 = (int)blockIdx.x * 64;            // m-tile
    const int head = (int)blockIdx.y >> 1;          // 0..23 = Q0..15,K0..3,V0..3
    const int h0 = ((int)blockIdx.y & 1) * 64;      // h-tile
    const float* src = (head < 16) ? WQ + (size_t)head * DM * DH
                     : (head < 20) ? WK + (size_t)(head - 16) * DM * DH
                                   : WV + (size_t)(head - 20) * DM * DH;
    {
        const int r = t >> 2, c = (t & 3) * 16;
        const float* p = src + (size_t)(m0 + r) * DH + h0 + c;
        #pragma unroll
        for (int kk = 0; kk < 4; ++kk) {
            float4 v = *(const float4*)(p + kk * 4);
            tl[r][c + kk * 4 + 0] = v.x; tl[r][c + kk * 4 + 1] = v.y;
            tl[r][c + kk * 4 + 2] = v.z; tl[r][c + kk * 4 + 3] = v.w;
        }
    }
    __syncthreads();
    {
        const int hh = t >> 2, ms = (t & 3) * 16;
        const int j = head * 128 + h0 + hh;         // concat row (Q|K|V)
        bf16 tmp[16];
        #pragma unroll
        for (int i = 0; i < 16; ++i) tmp[i] = f2bf(tl[ms + i][hh]);
        bf16* q = wt + (size_t)j * DM + m0 + ms;
        *(bf16x8*)q       = *(bf16x8*)&tmp[0];
        *(bf16x8*)(q + 8) = *(bf16x8*)&tmp[8];
    }
}

__global__ void prep_wo(const float* __restrict__ WO, bf16* __restrict__ wt) {
    __shared__ float tl[64][65];
    const int t = threadIdx.x;
    const int m0 = (int)blockIdx.x * 64;   // WO row tile ((n,h) dim)
    const int j0 = (int)blockIdx.y * 64;   // WO col tile (d_model)
    {
        const int r = t >> 2, c = (t & 3) * 16;
        const float* p = WO + (size_t)(m0 + r) * DM + j0 + c;
        #pragma unroll
        for (int kk = 0; kk < 4; ++kk) {
            float4 v = *(const float4*)(p + kk * 4);
            tl[r][c + kk * 4 + 0] = v.x; tl[r][c + kk * 4 + 1] = v.y;
            tl[r][c + kk * 4 + 2] = v.z; tl[r][c + kk * 4 + 3] = v.w;
        }
    }
    __syncthreads();
    {
        const int hh = t >> 2, ms = (t & 3) * 16;
        bf16 tmp[16];
        #pragma unroll
        for (int i = 0; i < 16; ++i) tmp[i] = f2bf(tl[ms + i][hh]);
        bf16* q = wt + (size_t)(j0 + hh) * DM + m0 + ms;
        *(bf16x8*)q       = *(bf16x8*)&tmp[0];
        *(bf16x8*)(q + 8) = *(bf16x8*)&tmp[8];
    }
}

// ---------------- rotary cos/sin table + bias concat (merged) ----------------
__global__ void sctab(float2* __restrict__ tab,
                      const float* __restrict__ bQ, const float* __restrict__ bK,
                      const float* __restrict__ bV, float* __restrict__ bias) {
    int idx = blockIdx.x * 256 + threadIdx.x;   // 0..262143
    int s = idx >> 6, i = idx & 63;
    float inv_freq = __expf(-(float)i * 0.14391156831212788f);
    float ang = (float)s * inv_freq;
    float2 cs;
    cs.x = cosf(ang);
    cs.y = sinf(ang);
    tab[idx] = cs;
    if (idx < NC)
        bias[idx] = (idx < KOFF) ? bQ[idx] : (idx < VOFF ? bK[idx - KOFF] : bV[idx - VOFF]);
}

// ---------------- GEMM: C[M][N] = A[M][2048] * Bt[N][2048]^T + bias ----------------
// 2-phase 128x128, (256,3) = 3 blocks/CU (r12: -16.5us). 1D grid + XCD-aware
// column-chunked swizzle (T1): assuming round-robin block->XCD dispatch
// (id%8 = xcd), XCD k owns bx in [k*NBX/8, (k+1)*NBX/8) for ALL by -> its B
// panels (NBX/8 x 512KB <= 1.5MB) stay L2-resident the whole kernel, and
// consecutive per-XCD blocks share the A panel. Bijective: (k,j)<->(bx,by).
// ROT=1: fused rotary epilogue; V cols (n0>=VOFF) write transposed to vtq.
#define BM 128
#define BN 128
#define BK 64
#define VTL 132   // vtile row stride (elems)

template <typename OutT, int ROT, int NBX>
__global__ __launch_bounds__(256, 3)
void gemm_bt(const bf16* __restrict__ A, const bf16* __restrict__ Bt,
             const float* __restrict__ bias, OutT* __restrict__ C, int N,
             const float2* __restrict__ tab, bf16* __restrict__ vtq) {
    __shared__ __align__(16) char smemraw[33792];  // As|Bs (32KB) / vtile [128][132]
    bf16* As = (bf16*)smemraw;
    bf16* Bs = (bf16*)(smemraw + 16384);
    const int tid = threadIdx.x;
    const int wave = tid >> 6, lane = tid & 63;
    const int quad = lane >> 4, l15 = lane & 15;
    const int wm = (wave >> 1) * 64, wn = (wave & 1) * 64;

    // XCD column-chunk swizzle (NBX % 8 == 0 required: 24, 16 both ok)
    const int id = (int)blockIdx.x;
    const int xk = id & 7;                 // xcd under round-robin dispatch
    const int j  = id >> 3;
    const int CPX = NBX / 8;               // bx columns per xcd
    const int bx = CPX * xk + (j % CPX);
    const int by = j / CPX;
    const int m0 = by * BM, n0 = bx * BN;

    f32x4 acc[4][4] = {};

    const bf16* gsrc = (wave < 2)
        ? A  + (size_t)(m0 + (wave & 1) * 64) * DM
        : Bt + (size_t)(n0 + (wave & 1) * 64) * DM;
    bf16* lbase = (wave < 2 ? As : Bs) + (wave & 1) * 64 * BK;
    const int lrow = lane >> 3;                          // 0..7
    const int gslot = (lane & 7) ^ lrow;                 // swizzled source slot
    const bf16* gp = gsrc + (size_t)lrow * DM + gslot * 8;

    const int rsw = l15 & 7;

    for (int k0 = 0; k0 < DM; k0 += BK) {
        __syncthreads();
        #pragma unroll
        for (int cc = 0; cc < 8; ++cc)
            load_lds16(gp + (size_t)cc * 8 * DM + k0, lbase + cc * 8 * BK);
        __syncthreads();

        #pragma unroll
        for (int ks = 0; ks < 2; ++ks) {
            bf16x8 af[4], bfr[4];
            #pragma unroll
            for (int i = 0; i < 4; ++i)
                af[i] = *(const bf16x8*)&As[(wm + i * 16 + l15) * BK + (((ks * 4 + quad) ^ rsw) * 8)];
            #pragma unroll
            for (int jj = 0; jj < 4; ++jj)
                bfr[jj] = *(const bf16x8*)&Bs[(wn + jj * 16 + l15) * BK + (((ks * 4 + quad) ^ rsw) * 8)];
            #pragma unroll
            for (int i = 0; i < 4; ++i)
                #pragma unroll
                for (int jj = 0; jj < 4; ++jj)
                    acc[i][jj] = __builtin_amdgcn_mfma_f32_16x16x32_bf16(af[i], bfr[jj], acc[i][jj], 0, 0, 0);
        }
    }

    if (ROT && n0 >= VOFF) {
        // ---- V tile: write transposed to vtq[vcol][s] via LDS ----
        __syncthreads();                       // all waves done with As/Bs
        bf16* vtile = (bf16*)smemraw;          // [128 cols][VTL]
        #pragma unroll
        for (int i = 0; i < 4; ++i) {
            const int rl0 = wm + i * 16 + quad * 4;
            #pragma unroll
            for (int jj = 0; jj < 4; ++jj) {
                const int cl = wn + jj * 16 + l15;
                const float bv = bias[n0 + cl];
                ushort4 w;
                bf16 h;
                h = f2bf(acc[i][jj][0] + bv); w.x = *(unsigned short*)&h;
                h = f2bf(acc[i][jj][1] + bv); w.y = *(unsigned short*)&h;
                h = f2bf(acc[i][jj][2] + bv); w.z = *(unsigned short*)&h;
                h = f2bf(acc[i][jj][3] + bv); w.w = *(unsigned short*)&h;
                *(ushort4*)&vtile[cl * VTL + rl0] = w;
            }
        }
        __syncthreads();
        // coalesced-ish store: 8 lanes cover 128B of one col per pass
        #pragma unroll
        for (int p = 0; p < 4; ++p) {
            const int c = p * 32 + (tid >> 3);
            const int s = (tid & 7) * 16;
            bf16* dst = vtq + (size_t)(n0 - VOFF + c) * SEQ + m0 + s;
            const bf16* srcl = vtile + c * VTL + s;
            *(bf16x8*)dst       = *(const bf16x8*)srcl;
            *(bf16x8*)(dst + 8) = *(const bf16x8*)(srcl + 8);
        }
        return;
    }

    const bool doRot = ROT && (n0 < VOFF);
    const float scl = (n0 < KOFF) ? Q_SCALE : 1.0f;

    #pragma unroll
    for (int i = 0; i < 4; ++i) {
        int row = m0 + wm + i * 16 + quad * 4;
        #pragma unroll
        for (int jj = 0; jj < 4; ++jj) {
            int col = n0 + wn + jj * 16 + l15;
            float bv = bias[col];
            if (ROT && doRot) {
                const int ii = (col >> 1) & 63;
                const bool odd = col & 1;
                #pragma unroll
                for (int r = 0; r < 4; ++r) {
                    float v = acc[i][jj][r] + bv;
                    float pv = __shfl_xor(v, 1);
                    float2 cs = tab[((row + r) << 6) + ii];
                    float o = odd ? (pv * cs.y + v * cs.x) : (v * cs.x - pv * cs.y);
                    C[(size_t)(row + r) * N + col] = (OutT)f2bf(o * scl);
                }
            } else {
                #pragma unroll
                for (int r = 0; r < 4; ++r) {
                    float val = acc[i][jj][r] + bv;
                    if constexpr (sizeof(OutT) == 2)
                        C[(size_t)(row + r) * N + col] = f2bf(val);
                    else
                        C[(size_t)(row + r) * N + col] = val;
                }
            }
        }
    }
}

// ---------------- flash attention v9 (frozen from r8: 110.2 us) ----------------
// 1024 blocks x 256 thr; block = (qt, g, hp), biggest-qt-first (LPT backfill).
// 4 waves = 2 ch x 2 kh. K/V via global_load_lds, XOR involution swizzle,
// swapped QK^T + in-reg P (T12), (256,3) cap = 3 blocks/CU (occupancy > spill).
__global__ __launch_bounds__(256, 3)
void flash(const bf16* __restrict__ qkv, const bf16* __restrict__ vt,
           bf16* __restrict__ z) {
    __shared__ char smem[33280];
    bf16*  Ks  = (bf16*)smem;                    // [64][128]  = 16384 B (swizzled)
    bf16*  Vs  = (bf16*)(smem + 16384);          // [128][64]  = 16384 B (swizzled)
    float* lml = (float*)(smem + 32768);         // 4 x 32     =   512 B
    float* ob  = (float*)smem;                   // merge reuse: 2*32*128 f32 = 32768 B

    const int tid = threadIdx.x;
    const int wave = tid >> 6, lane = tid & 63;
    const int l31 = lane & 31, lh = lane >> 5;
    const int ch = wave >> 1;         // row chunk (16 rows)
    const int kh = wave & 1;          // key half (32 keys)
    const int bx = blockIdx.x;
    const int qt = 127 - (bx >> 3);   // biggest first
    const int g = (bx >> 1) & 3;      // KV group
    const int hp = bx & 1;            // head pair within group
    const int r_base = qt * 32 + ch * 16;
    const int ktmax = qt >> 1;
    const int rsw = l31 & 7;          // read-side XOR (row&7 for both QK and PV reads)

    // staging pointers (3 total; folding: krow&7 repeats every 8 rows, vdd&7 is
    // chunk-independent)
    const int krow0 = wave * 16 + (lane >> 4);          // chunk i=0 row
    const int krow1 = krow0 + 4;                        // chunk i=1 row
    const bf16* kp0 = qkv + KOFF + g * DH + (size_t)krow0 * NC + (((lane & 15) ^ (krow0 & 7)) * 8);
    const bf16* kp1 = qkv + KOFF + g * DH + (size_t)krow1 * NC + (((lane & 15) ^ (krow1 & 7)) * 8);
    const int vdd0 = wave * 32 + (lane >> 3);           // chunk i=0 d-row
    const bf16* vp0 = vt + (size_t)(g * DH + vdd0) * SEQ + (((lane & 7) ^ ((lane >> 3) & 7)) * 8);

    // Q -> registers (B operand): lane n=l31 -> q-row; k = lh*8 + s*16 + j
    bf16x8 qf[8];
    {
        const int qrow = r_base + (l31 & 15);
        const int head = g * 4 + hp * 2 + (l31 >> 4);
        const bf16* qp = qkv + (size_t)qrow * NC + head * DH + lh * 8;
        #pragma unroll
        for (int s = 0; s < 8; ++s)
            qf[s] = *(const bf16x8*)(qp + s * 16);
    }

    f32x16 o_acc[4] = {};
    float lsum = 0.0f;

    for (int kt = 0; kt <= ktmax; ++kt) {
        __syncthreads();   // all waves done reading Ks/Vs of prev iter
        load_lds16(kp0,                        Ks + (wave * 4 + 0) * 512);
        load_lds16(kp1,                        Ks + (wave * 4 + 1) * 512);
        load_lds16(kp0 + (size_t)8 * NC,       Ks + (wave * 4 + 2) * 512);
        load_lds16(kp1 + (size_t)8 * NC,       Ks + (wave * 4 + 3) * 512);
        load_lds16(vp0,                        Vs + (wave * 4 + 0) * 512);
        load_lds16(vp0 + (size_t)8 * SEQ,      Vs + (wave * 4 + 1) * 512);
        load_lds16(vp0 + (size_t)16 * SEQ,     Vs + (wave * 4 + 2) * 512);
        load_lds16(vp0 + (size_t)24 * SEQ,     Vs + (wave * 4 + 3) * 512);
        __syncthreads();   // compiler drains vmcnt(0) before barrier
        kp0 += (size_t)64 * NC; kp1 += (size_t)64 * NC; vp0 += 64;

        const int key_min = kt * 64 + kh * 32;
        if (key_min <= r_base + 15) {   // some key unmasked for this chunk
            // S^T = K Q^T : lane l31 = q-row, regs = 16 keys
            f32x16 sacc = {};
            __builtin_amdgcn_s_setprio(1);
            #pragma unroll
            for (int s = 0; s < 8; ++s) {
                bf16x8 kb = *(const bf16x8*)&Ks[(kh * 32 + l31) * 128 + (((lh + 2 * s) ^ rsw) * 8)];
                sacc = __builtin_amdgcn_mfma_f32_32x32x16_bf16(kb, qf[s], sacc, 0, 0, 0);
            }
            __builtin_amdgcn_s_setprio(0);

            const bool needmask = (key_min + 31 > r_base);
            const int qrow = r_base + (l31 & 15);
            float e[16];
            if (needmask) {   // diagonal tile only (~1 of ~33 iters)
                #pragma unroll
                for (int rg = 0; rg < 16; ++rg) {
                    const int keyg = key_min + (rg & 3) + 8 * (rg >> 2) + 4 * lh;
                    float sv = sacc[rg];
                    if (keyg > qrow) sv = -INFINITY;
                    e[rg] = exp2f(sv);
                }
            } else {
                #pragma unroll
                for (int rg = 0; rg < 16; ++rg)
                    e[rg] = exp2f(sacc[rg]);
            }
            {
                float t0 = (e[0] + e[1]) + (e[2] + e[3]);
                float t1 = (e[4] + e[5]) + (e[6] + e[7]);
                float t2 = (e[8] + e[9]) + (e[10] + e[11]);
                float t3 = (e[12] + e[13]) + (e[14] + e[15]);
                lsum += (t0 + t1) + (t2 + t3);
            }

            // P -> A fragments in-register (T12)
            bf16x8 pa[2];
            #pragma unroll
            for (int s2 = 0; s2 < 2; ++s2) {
                uint32_t wA0, wA1, wB0, wB1;
                asm("v_cvt_pk_bf16_f32 %0, %1, %2" : "=v"(wA0) : "v"(e[8*s2+0]), "v"(e[8*s2+1]));
                asm("v_cvt_pk_bf16_f32 %0, %1, %2" : "=v"(wA1) : "v"(e[8*s2+2]), "v"(e[8*s2+3]));
                asm("v_cvt_pk_bf16_f32 %0, %1, %2" : "=v"(wB0) : "v"(e[8*s2+4]), "v"(e[8*s2+5]));
                asm("v_cvt_pk_bf16_f32 %0, %1, %2" : "=v"(wB1) : "v"(e[8*s2+6]), "v"(e[8*s2+7]));
                asm volatile("v_permlane32_swap_b32 %0, %1" : "+v"(wA0), "+v"(wB0));
                asm volatile("v_permlane32_swap_b32 %0, %1" : "+v"(wA1), "+v"(wB1));
                union { uint32_t u[4]; bf16x8 v; } cvt;
                cvt.u[0] = wA0; cvt.u[1] = wA1; cvt.u[2] = wB0; cvt.u[3] = wB1;
                pa[s2] = cvt.v;
            }

            // PV: A = P fragments (in-reg), B = V^T fragments from LDS
            __builtin_amdgcn_s_setprio(1);
            #pragma unroll
            for (int nt = 0; nt < 4; ++nt) {
                #pragma unroll
                for (int s2 = 0; s2 < 2; ++s2) {
                    bf16x8 vb = *(const bf16x8*)&Vs[(nt * 32 + l31) * 64 + (((kh * 4 + lh + 2 * s2) ^ rsw) * 8)];
                    o_acc[nt] = __builtin_amdgcn_mfma_f32_32x32x16_bf16(pa[s2], vb, o_acc[nt], 0, 0, 0);
                }
            }
            __builtin_amdgcn_s_setprio(0);
        }
    }

    // merge lh halves of l in-register
    float la = lsum, lb = lsum;
    asm volatile("v_permlane32_swap_b32 %0, %1" : "+v"(la), "+v"(lb));
    const float l_tot = la + lb;   // full 32-key-half sum for q-row l31

    // ---- merge key-half partials (linear: no max alignment needed) ----
    __syncthreads();               // all compute done; Ks/Vs region free for ob
    if (lh == 0) lml[wave * 32 + l31] = l_tot;
    if (kh == 1) {
        #pragma unroll
        for (int nt = 0; nt < 4; ++nt)
            #pragma unroll
            for (int rg = 0; rg < 16; ++rg) {
                const int m = (rg & 3) + 8 * (rg >> 2) + 4 * lh;
                ob[(ch * 32 + m) * 128 + nt * 32 + l31] = o_acc[nt][rg];
            }
    }
    __syncthreads();
    if (kh == 0) {
        float invl[16];
        #pragma unroll
        for (int rg = 0; rg < 16; ++rg) {
            const int m = (rg & 3) + 8 * (rg >> 2) + 4 * lh;
            invl[rg] = 1.0f / (lml[wave * 32 + m] + lml[(wave + 1) * 32 + m]);
        }
        #pragma unroll
        for (int nt = 0; nt < 4; ++nt)
            #pragma unroll
            for (int rg = 0; rg < 16; ++rg) {
                const int m = (rg & 3) + 8 * (rg >> 2) + 4 * lh;
                float oo = o_acc[nt][rg] + ob[(ch * 32 + m) * 128 + nt * 32 + l31];
                const int row = r_base + (m & 15);
                const int col = (g * 4 + hp * 2 + (m >> 4)) * DH + nt * 32 + l31;
                z[(size_t)row * DM + col] = f2bf(oo * invl[rg]);
            }
    }
}

// ---------------- launch ----------------
extern "C" void kernel_launch(void* const* d_in, const int* in_sizes, int n_in,
                              void* d_out, int out_size, void* d_ws, size_t ws_size,
                              hipStream_t stream) {
    const float* x  = (const float*)d_in[0];
    const float* WQ = (const float*)d_in[1];
    const float* WK = (const float*)d_in[2];
    const float* WV = (const float*)d_in[3];
    const float* WO = (const float*)d_in[4];
    const float* bQ = (const float*)d_in[5];
    const float* bK = (const float*)d_in[6];
    const float* bV = (const float*)d_in[7];
    const float* bO = (const float*)d_in[8];
    float* out = (float*)d_out;

    char* ws = (char*)d_ws;
    bf16*  wt_cat = (bf16*)(ws);                  // 12,582,912
    bf16*  wt_o   = (bf16*)(ws + 12582912);       //  8,388,608
    float* bias_c = (float*)(ws + 20971520);      //  16,384 (padded)
    bf16*  qkv    = (bf16*)(ws + 20987904);       // 25,165,824
    bf16*  vt     = (bf16*)(ws + 46153728);       //  4,194,304 (written by gemm1 V-epilogue)
    bf16*  z      = (bf16*)(ws + 50348032);       // 16,777,216
    bf16*  xb     = (bf16*)(ws + 67125248);       // 16,777,216
    float2* sct   = (float2*)z;                   // 2,097,152: z region dead until
                                                  // flash; sct dead after gemm1

    xconv    <<<8192, 256, 0, stream>>>(x, xb);
    prep_wqkv<<<dim3(32, 48), 256, 0, stream>>>(WQ, WK, WV, wt_cat);
    prep_wo  <<<dim3(32, 32), 256, 0, stream>>>(WO, wt_o);
    sctab    <<<1024, 256, 0, stream>>>(sct, bQ, bK, bV, bias_c);
    gemm_bt<bf16, 1, 24> <<<768, 256, 0, stream>>>(xb, wt_cat, bias_c, qkv, NC, sct, vt);
    flash    <<<1024, 256, 0, stream>>>(qkv, vt, z);
    gemm_bt<float, 0, 16><<<512, 256, 0, stream>>>(z, wt_o, bO, out, DM, nullptr, nullptr);
}

// Round 14
// 321.274 us; speedup vs baseline: 1.0523x; 1.0523x over previous
//
#include <hip/hip_runtime.h>
#include <hip/hip_bf16.h>
#include <cstdint>
#include <cstddef>

#define SEQ    4096
#define DM     2048
#define DH     128
#define NH     16
#define NKV    4
#define NC     3072          // qkv output columns: 2048 q | 512 k | 512 v
#define KOFF   2048
#define VOFF   2560
// 1/sqrt(128) * log2(e): q pre-scale so softmax runs in base-2 (exp2)
#define Q_SCALE 0.12751730f

using bf16 = __hip_bfloat16;
typedef __bf16 bf16x8 __attribute__((ext_vector_type(8)));
typedef float f32x4 __attribute__((ext_vector_type(4)));
typedef float f32x16 __attribute__((ext_vector_type(16)));

static __device__ inline float bf2f(bf16 x) { return __bfloat162float(x); }
static __device__ inline bf16 f2bf(float x) { return __float2bfloat16(x); }

// async global->LDS, 16B per lane. LDS dest = wave-uniform base + lane*16.
static __device__ inline void load_lds16(const bf16* g, bf16* l) {
    __builtin_amdgcn_global_load_lds(
        (const __attribute__((address_space(1))) uint32_t*)g,
        (__attribute__((address_space(3))) uint32_t*)l, 16, 0, 0);
}

// ---------------- prep_all: wqkv-T | wo-T | sctab+bias | xconv in ONE dispatch ----
// Block-range branching (block-uniform). Saves 3 launch gaps vs r12's 4 kernels.
// blocks [0,1536): prep_wqkv 64x64 tile transpose (f32->bf16)
// blocks [1536,2560): prep_wo transpose
// blocks [2560,3584): sctab (rotary cos/sin table) + bias concat
// blocks [3584,11776): xconv f32->bf16
__global__ __launch_bounds__(256)
void prep_all(const float* __restrict__ x, bf16* __restrict__ xb,
              const float* __restrict__ WQ, const float* __restrict__ WK,
              const float* __restrict__ WV, bf16* __restrict__ wt,
              const float* __restrict__ WO, bf16* __restrict__ wto,
              float2* __restrict__ tab, const float* __restrict__ bQ,
              const float* __restrict__ bK, const float* __restrict__ bV,
              float* __restrict__ bias) {
    __shared__ float tl[64][65];
    const int bid = (int)blockIdx.x;
    const int t = threadIdx.x;

    if (bid < 1536) {
        // ---- prep_wqkv: m-tile = bid&31, y = bid>>5 (head, h-half) ----
        const int m0 = (bid & 31) * 64;
        const int yy = bid >> 5;                    // 0..47
        const int head = yy >> 1;                   // 0..23 = Q0..15,K0..3,V0..3
        const int h0 = (yy & 1) * 64;
        const float* src = (head < 16) ? WQ + (size_t)head * DM * DH
                         : (head < 20) ? WK + (size_t)(head - 16) * DM * DH
                                       : WV + (size_t)(head - 20) * DM * DH;
        {
            const int r = t >> 2, c = (t & 3) * 16;
            const float* p = src + (size_t)(m0 + r) * DH + h0 + c;
            #pragma unroll
            for (int kk = 0; kk < 4; ++kk) {
                float4 v = *(const float4*)(p + kk * 4);
                tl[r][c + kk * 4 + 0] = v.x; tl[r][c + kk * 4 + 1] = v.y;
                tl[r][c + kk * 4 + 2] = v.z; tl[r][c + kk * 4 + 3] = v.w;
            }
        }
        __syncthreads();
        {
            const int hh = t >> 2, ms = (t & 3) * 16;
            const int j = head * 128 + h0 + hh;     // concat row (Q|K|V)
            bf16 tmp[16];
            #pragma unroll
            for (int i = 0; i < 16; ++i) tmp[i] = f2bf(tl[ms + i][hh]);
            bf16* q = wt + (size_t)j * DM + m0 + ms;
            *(bf16x8*)q       = *(bf16x8*)&tmp[0];
            *(bf16x8*)(q + 8) = *(bf16x8*)&tmp[8];
        }
    } else if (bid < 2560) {
        // ---- prep_wo: idx = bid-1536; m0 = (idx&31)*64, j0 = (idx>>5)*64 ----
        const int idx = bid - 1536;
        const int m0 = (idx & 31) * 64;
        const int j0 = (idx >> 5) * 64;
        {
            const int r = t >> 2, c = (t & 3) * 16;
            const float* p = WO + (size_t)(m0 + r) * DM + j0 + c;
            #pragma unroll
            for (int kk = 0; kk < 4; ++kk) {
                float4 v = *(const float4*)(p + kk * 4);
                tl[r][c + kk * 4 + 0] = v.x; tl[r][c + kk * 4 + 1] = v.y;
                tl[r][c + kk * 4 + 2] = v.z; tl[r][c + kk * 4 + 3] = v.w;
            }
        }
        __syncthreads();
        {
            const int hh = t >> 2, ms = (t & 3) * 16;
            bf16 tmp[16];
            #pragma unroll
            for (int i = 0; i < 16; ++i) tmp[i] = f2bf(tl[ms + i][hh]);
            bf16* q = wto + (size_t)(j0 + hh) * DM + m0 + ms;
            *(bf16x8*)q       = *(bf16x8*)&tmp[0];
            *(bf16x8*)(q + 8) = *(bf16x8*)&tmp[8];
        }
    } else if (bid < 3584) {
        // ---- sctab + bias concat: idx in [0, 262144) ----
        const int idx = (bid - 2560) * 256 + t;
        const int s = idx >> 6, i = idx & 63;
        float inv_freq = __expf(-(float)i * 0.14391156831212788f);
        float ang = (float)s * inv_freq;
        float2 cs;
        cs.x = cosf(ang);
        cs.y = sinf(ang);
        tab[idx] = cs;
        if (idx < NC)
            bias[idx] = (idx < KOFF) ? bQ[idx] : (idx < VOFF ? bK[idx - KOFF] : bV[idx - VOFF]);
    } else {
        // ---- xconv: one float4 per thread ----
        const int i = (bid - 3584) * 256 + t;
        float4 v = ((const float4*)x)[i];
        bf16 a = f2bf(v.x), b = f2bf(v.y), c = f2bf(v.z), d = f2bf(v.w);
        ushort4 u;
        u.x = *(unsigned short*)&a; u.y = *(unsigned short*)&b;
        u.z = *(unsigned short*)&c; u.w = *(unsigned short*)&d;
        ((ushort4*)xb)[i] = u;
    }
}

// ---------------- GEMM: C[M][N] = A[M][2048] * Bt[N][2048]^T + bias ----------------
// 2-phase 128x128, 2D grid (bx fastest -- default dispatch locality measured best;
// r13: XCD column-chunk swizzle REGRESSED +12.5us, L3-fit regime). (256,3) = 3
// blocks/CU (r12: -16.5us). ROT=1: fused rotary epilogue for q/k cols; V cols
// (n0>=VOFF) write TRANSPOSED into vtq[vcol][s] via LDS round-trip.
#define BM 128
#define BN 128
#define BK 64
#define VTL 132   // vtile row stride (elems)

template <typename OutT, int ROT>
__global__ __launch_bounds__(256, 3)
void gemm_bt(const bf16* __restrict__ A, const bf16* __restrict__ Bt,
             const float* __restrict__ bias, OutT* __restrict__ C, int N,
             const float2* __restrict__ tab, bf16* __restrict__ vtq) {
    __shared__ __align__(16) char smemraw[33792];  // As|Bs (32KB) / vtile [128][132]
    bf16* As = (bf16*)smemraw;
    bf16* Bs = (bf16*)(smemraw + 16384);
    const int tid = threadIdx.x;
    const int wave = tid >> 6, lane = tid & 63;
    const int quad = lane >> 4, l15 = lane & 15;
    const int wm = (wave >> 1) * 64, wn = (wave & 1) * 64;
    const int m0 = blockIdx.y * BM, n0 = blockIdx.x * BN;

    f32x4 acc[4][4] = {};

    const bf16* gsrc = (wave < 2)
        ? A  + (size_t)(m0 + (wave & 1) * 64) * DM
        : Bt + (size_t)(n0 + (wave & 1) * 64) * DM;
    bf16* lbase = (wave < 2 ? As : Bs) + (wave & 1) * 64 * BK;
    const int lrow = lane >> 3;                          // 0..7
    const int gslot = (lane & 7) ^ lrow;                 // swizzled source slot
    const bf16* gp = gsrc + (size_t)lrow * DM + gslot * 8;

    const int rsw = l15 & 7;

    for (int k0 = 0; k0 < DM; k0 += BK) {
        __syncthreads();
        #pragma unroll
        for (int cc = 0; cc < 8; ++cc)
            load_lds16(gp + (size_t)cc * 8 * DM + k0, lbase + cc * 8 * BK);
        __syncthreads();

        #pragma unroll
        for (int ks = 0; ks < 2; ++ks) {
            bf16x8 af[4], bfr[4];
            #pragma unroll
            for (int i = 0; i < 4; ++i)
                af[i] = *(const bf16x8*)&As[(wm + i * 16 + l15) * BK + (((ks * 4 + quad) ^ rsw) * 8)];
            #pragma unroll
            for (int j = 0; j < 4; ++j)
                bfr[j] = *(const bf16x8*)&Bs[(wn + j * 16 + l15) * BK + (((ks * 4 + quad) ^ rsw) * 8)];
            #pragma unroll
            for (int i = 0; i < 4; ++i)
                #pragma unroll
                for (int j = 0; j < 4; ++j)
                    acc[i][j] = __builtin_amdgcn_mfma_f32_16x16x32_bf16(af[i], bfr[j], acc[i][j], 0, 0, 0);
        }
    }

    if (ROT && n0 >= VOFF) {
        // ---- V tile: write transposed to vtq[vcol][s] via LDS ----
        __syncthreads();                       // all waves done with As/Bs
        bf16* vtile = (bf16*)smemraw;          // [128 cols][VTL]
        #pragma unroll
        for (int i = 0; i < 4; ++i) {
            const int rl0 = wm + i * 16 + quad * 4;
            #pragma unroll
            for (int j = 0; j < 4; ++j) {
                const int cl = wn + j * 16 + l15;
                const float bv = bias[n0 + cl];
                ushort4 w;
                bf16 h;
                h = f2bf(acc[i][j][0] + bv); w.x = *(unsigned short*)&h;
                h = f2bf(acc[i][j][1] + bv); w.y = *(unsigned short*)&h;
                h = f2bf(acc[i][j][2] + bv); w.z = *(unsigned short*)&h;
                h = f2bf(acc[i][j][3] + bv); w.w = *(unsigned short*)&h;
                *(ushort4*)&vtile[cl * VTL + rl0] = w;
            }
        }
        __syncthreads();
        // coalesced-ish store: 8 lanes cover 128B of one col per pass
        #pragma unroll
        for (int p = 0; p < 4; ++p) {
            const int c = p * 32 + (tid >> 3);
            const int s = (tid & 7) * 16;
            bf16* dst = vtq + (size_t)(n0 - VOFF + c) * SEQ + m0 + s;
            const bf16* srcl = vtile + c * VTL + s;
            *(bf16x8*)dst       = *(const bf16x8*)srcl;
            *(bf16x8*)(dst + 8) = *(const bf16x8*)(srcl + 8);
        }
        return;
    }

    const bool doRot = ROT && (n0 < VOFF);
    const float scl = (n0 < KOFF) ? Q_SCALE : 1.0f;

    #pragma unroll
    for (int i = 0; i < 4; ++i) {
        int row = m0 + wm + i * 16 + quad * 4;
        #pragma unroll
        for (int j = 0; j < 4; ++j) {
            int col = n0 + wn + j * 16 + l15;
            float bv = bias[col];
            if (ROT && doRot) {
                const int ii = (col >> 1) & 63;
                const bool odd = col & 1;
                #pragma unroll
                for (int r = 0; r < 4; ++r) {
                    float v = acc[i][j][r] + bv;
                    float pv = __shfl_xor(v, 1);
                    float2 cs = tab[((row + r) << 6) + ii];
                    float o = odd ? (pv * cs.y + v * cs.x) : (v * cs.x - pv * cs.y);
                    C[(size_t)(row + r) * N + col] = (OutT)f2bf(o * scl);
                }
            } else {
                #pragma unroll
                for (int r = 0; r < 4; ++r) {
                    float val = acc[i][j][r] + bv;
                    if constexpr (sizeof(OutT) == 2)
                        C[(size_t)(row + r) * N + col] = f2bf(val);
                    else
                        C[(size_t)(row + r) * N + col] = val;
                }
            }
        }
    }
}

// ---------------- flash attention v9 (frozen from r8: 110.2 us) ----------------
// 1024 blocks x 256 thr; block = (qt, g, hp), biggest-qt-first (LPT backfill).
// 4 waves = 2 ch x 2 kh. K/V via global_load_lds, XOR involution swizzle,
// swapped QK^T + in-reg P (T12), (256,3) cap = 3 blocks/CU (occupancy > spill).
__global__ __launch_bounds__(256, 3)
void flash(const bf16* __restrict__ qkv, const bf16* __restrict__ vt,
           bf16* __restrict__ z) {
    __shared__ char smem[33280];
    bf16*  Ks  = (bf16*)smem;                    // [64][128]  = 16384 B (swizzled)
    bf16*  Vs  = (bf16*)(smem + 16384);          // [128][64]  = 16384 B (swizzled)
    float* lml = (float*)(smem + 32768);         // 4 x 32     =   512 B
    float* ob  = (float*)smem;                   // merge reuse: 2*32*128 f32 = 32768 B

    const int tid = threadIdx.x;
    const int wave = tid >> 6, lane = tid & 63;
    const int l31 = lane & 31, lh = lane >> 5;
    const int ch = wave >> 1;         // row chunk (16 rows)
    const int kh = wave & 1;          // key half (32 keys)
    const int bx = blockIdx.x;
    const int qt = 127 - (bx >> 3);   // biggest first
    const int g = (bx >> 1) & 3;      // KV group
    const int hp = bx & 1;            // head pair within group
    const int r_base = qt * 32 + ch * 16;
    const int ktmax = qt >> 1;
    const int rsw = l31 & 7;          // read-side XOR (row&7 for both QK and PV reads)

    // staging pointers (3 total; folding: krow&7 repeats every 8 rows, vdd&7 is
    // chunk-independent)
    const int krow0 = wave * 16 + (lane >> 4);          // chunk i=0 row
    const int krow1 = krow0 + 4;                        // chunk i=1 row
    const bf16* kp0 = qkv + KOFF + g * DH + (size_t)krow0 * NC + (((lane & 15) ^ (krow0 & 7)) * 8);
    const bf16* kp1 = qkv + KOFF + g * DH + (size_t)krow1 * NC + (((lane & 15) ^ (krow1 & 7)) * 8);
    const int vdd0 = wave * 32 + (lane >> 3);           // chunk i=0 d-row
    const bf16* vp0 = vt + (size_t)(g * DH + vdd0) * SEQ + (((lane & 7) ^ ((lane >> 3) & 7)) * 8);

    // Q -> registers (B operand): lane n=l31 -> q-row; k = lh*8 + s*16 + j
    bf16x8 qf[8];
    {
        const int qrow = r_base + (l31 & 15);
        const int head = g * 4 + hp * 2 + (l31 >> 4);
        const bf16* qp = qkv + (size_t)qrow * NC + head * DH + lh * 8;
        #pragma unroll
        for (int s = 0; s < 8; ++s)
            qf[s] = *(const bf16x8*)(qp + s * 16);
    }

    f32x16 o_acc[4] = {};
    float lsum = 0.0f;

    for (int kt = 0; kt <= ktmax; ++kt) {
        __syncthreads();   // all waves done reading Ks/Vs of prev iter
        load_lds16(kp0,                        Ks + (wave * 4 + 0) * 512);
        load_lds16(kp1,                        Ks + (wave * 4 + 1) * 512);
        load_lds16(kp0 + (size_t)8 * NC,       Ks + (wave * 4 + 2) * 512);
        load_lds16(kp1 + (size_t)8 * NC,       Ks + (wave * 4 + 3) * 512);
        load_lds16(vp0,                        Vs + (wave * 4 + 0) * 512);
        load_lds16(vp0 + (size_t)8 * SEQ,      Vs + (wave * 4 + 1) * 512);
        load_lds16(vp0 + (size_t)16 * SEQ,     Vs + (wave * 4 + 2) * 512);
        load_lds16(vp0 + (size_t)24 * SEQ,     Vs + (wave * 4 + 3) * 512);
        __syncthreads();   // compiler drains vmcnt(0) before barrier
        kp0 += (size_t)64 * NC; kp1 += (size_t)64 * NC; vp0 += 64;

        const int key_min = kt * 64 + kh * 32;
        if (key_min <= r_base + 15) {   // some key unmasked for this chunk
            // S^T = K Q^T : lane l31 = q-row, regs = 16 keys
            f32x16 sacc = {};
            __builtin_amdgcn_s_setprio(1);
            #pragma unroll
            for (int s = 0; s < 8; ++s) {
                bf16x8 kb = *(const bf16x8*)&Ks[(kh * 32 + l31) * 128 + (((lh + 2 * s) ^ rsw) * 8)];
                sacc = __builtin_amdgcn_mfma_f32_32x32x16_bf16(kb, qf[s], sacc, 0, 0, 0);
            }
            __builtin_amdgcn_s_setprio(0);

            const bool needmask = (key_min + 31 > r_base);
            const int qrow = r_base + (l31 & 15);
            float e[16];
            if (needmask) {   // diagonal tile only (~1 of ~33 iters)
                #pragma unroll
                for (int rg = 0; rg < 16; ++rg) {
                    const int keyg = key_min + (rg & 3) + 8 * (rg >> 2) + 4 * lh;
                    float sv = sacc[rg];
                    if (keyg > qrow) sv = -INFINITY;
                    e[rg] = exp2f(sv);
                }
            } else {
                #pragma unroll
                for (int rg = 0; rg < 16; ++rg)
                    e[rg] = exp2f(sacc[rg]);
            }
            {
                float t0 = (e[0] + e[1]) + (e[2] + e[3]);
                float t1 = (e[4] + e[5]) + (e[6] + e[7]);
                float t2 = (e[8] + e[9]) + (e[10] + e[11]);
                float t3 = (e[12] + e[13]) + (e[14] + e[15]);
                lsum += (t0 + t1) + (t2 + t3);
            }

            // P -> A fragments in-register (T12)
            bf16x8 pa[2];
            #pragma unroll
            for (int s2 = 0; s2 < 2; ++s2) {
                uint32_t wA0, wA1, wB0, wB1;
                asm("v_cvt_pk_bf16_f32 %0, %1, %2" : "=v"(wA0) : "v"(e[8*s2+0]), "v"(e[8*s2+1]));
                asm("v_cvt_pk_bf16_f32 %0, %1, %2" : "=v"(wA1) : "v"(e[8*s2+2]), "v"(e[8*s2+3]));
                asm("v_cvt_pk_bf16_f32 %0, %1, %2" : "=v"(wB0) : "v"(e[8*s2+4]), "v"(e[8*s2+5]));
                asm("v_cvt_pk_bf16_f32 %0, %1, %2" : "=v"(wB1) : "v"(e[8*s2+6]), "v"(e[8*s2+7]));
                asm volatile("v_permlane32_swap_b32 %0, %1" : "+v"(wA0), "+v"(wB0));
                asm volatile("v_permlane32_swap_b32 %0, %1" : "+v"(wA1), "+v"(wB1));
                union { uint32_t u[4]; bf16x8 v; } cvt;
                cvt.u[0] = wA0; cvt.u[1] = wA1; cvt.u[2] = wB0; cvt.u[3] = wB1;
                pa[s2] = cvt.v;
            }

            // PV: A = P fragments (in-reg), B = V^T fragments from LDS
            __builtin_amdgcn_s_setprio(1);
            #pragma unroll
            for (int nt = 0; nt < 4; ++nt) {
                #pragma unroll
                for (int s2 = 0; s2 < 2; ++s2) {
                    bf16x8 vb = *(const bf16x8*)&Vs[(nt * 32 + l31) * 64 + (((kh * 4 + lh + 2 * s2) ^ rsw) * 8)];
                    o_acc[nt] = __builtin_amdgcn_mfma_f32_32x32x16_bf16(pa[s2], vb, o_acc[nt], 0, 0, 0);
                }
            }
            __builtin_amdgcn_s_setprio(0);
        }
    }

    // merge lh halves of l in-register
    float la = lsum, lb = lsum;
    asm volatile("v_permlane32_swap_b32 %0, %1" : "+v"(la), "+v"(lb));
    const float l_tot = la + lb;   // full 32-key-half sum for q-row l31

    // ---- merge key-half partials (linear: no max alignment needed) ----
    __syncthreads();               // all compute done; Ks/Vs region free for ob
    if (lh == 0) lml[wave * 32 + l31] = l_tot;
    if (kh == 1) {
        #pragma unroll
        for (int nt = 0; nt < 4; ++nt)
            #pragma unroll
            for (int rg = 0; rg < 16; ++rg) {
                const int m = (rg & 3) + 8 * (rg >> 2) + 4 * lh;
                ob[(ch * 32 + m) * 128 + nt * 32 + l31] = o_acc[nt][rg];
            }
    }
    __syncthreads();
    if (kh == 0) {
        float invl[16];
        #pragma unroll
        for (int rg = 0; rg < 16; ++rg) {
            const int m = (rg & 3) + 8 * (rg >> 2) + 4 * lh;
            invl[rg] = 1.0f / (lml[wave * 32 + m] + lml[(wave + 1) * 32 + m]);
        }
        #pragma unroll
        for (int nt = 0; nt < 4; ++nt)
            #pragma unroll
            for (int rg = 0; rg < 16; ++rg) {
                const int m = (rg & 3) + 8 * (rg >> 2) + 4 * lh;
                float oo = o_acc[nt][rg] + ob[(ch * 32 + m) * 128 + nt * 32 + l31];
                const int row = r_base + (m & 15);
                const int col = (g * 4 + hp * 2 + (m >> 4)) * DH + nt * 32 + l31;
                z[(size_t)row * DM + col] = f2bf(oo * invl[rg]);
            }
    }
}

// ---------------- launch ----------------
extern "C" void kernel_launch(void* const* d_in, const int* in_sizes, int n_in,
                              void* d_out, int out_size, void* d_ws, size_t ws_size,
                              hipStream_t stream) {
    const float* x  = (const float*)d_in[0];
    const float* WQ = (const float*)d_in[1];
    const float* WK = (const float*)d_in[2];
    const float* WV = (const float*)d_in[3];
    const float* WO = (const float*)d_in[4];
    const float* bQ = (const float*)d_in[5];
    const float* bK = (const float*)d_in[6];
    const float* bV = (const float*)d_in[7];
    const float* bO = (const float*)d_in[8];
    float* out = (float*)d_out;

    char* ws = (char*)d_ws;
    bf16*  wt_cat = (bf16*)(ws);                  // 12,582,912
    bf16*  wt_o   = (bf16*)(ws + 12582912);       //  8,388,608
    float* bias_c = (float*)(ws + 20971520);      //  16,384 (padded)
    bf16*  qkv    = (bf16*)(ws + 20987904);       // 25,165,824
    bf16*  vt     = (bf16*)(ws + 46153728);       //  4,194,304 (written by gemm1 V-epilogue)
    bf16*  z      = (bf16*)(ws + 50348032);       // 16,777,216
    bf16*  xb     = (bf16*)(ws + 67125248);       // 16,777,216
    float2* sct   = (float2*)z;                   // 2,097,152: z region dead until
                                                  // flash; sct dead after gemm1

    prep_all <<<11776, 256, 0, stream>>>(x, xb, WQ, WK, WV, wt_cat, WO, wt_o,
                                         sct, bQ, bK, bV, bias_c);
    gemm_bt<bf16, 1> <<<dim3(24, 32), 256, 0, stream>>>(xb, wt_cat, bias_c, qkv, NC, sct, vt);
    flash    <<<1024, 256, 0, stream>>>(qkv, vt, z);
    gemm_bt<float, 0><<<dim3(16, 32), 256, 0, stream>>>(z, wt_o, bO, out, DM, nullptr, nullptr);
}